// Round 2
// baseline (856.721 us; speedup 1.0000x reference)
//
#include <hip/hip_runtime.h>
#include <cmath>

#define BB 8
#define NN 4096
#define DD 64
#define KK 8
#define NCLS 2

constexpr float LNEPS = 1e-5f;
constexpr float BNRS = 0.9999950000374994f;      // 1/sqrt(1+1e-5)
constexpr float INVSQRT2 = 0.70710678118654752440f;

constexpr int QKV_GRID = 512;
constexpr int ATTN_GRID = 1024;
constexpr int FFN_GRID = 512;

__device__ __forceinline__ float wave_sum(float v) {
#pragma unroll
  for (int m = 32; m > 0; m >>= 1) v += __shfl_xor(v, m, 64);
  return v;
}

__device__ __forceinline__ float gelu_exact(float x) {
  return 0.5f * x * (1.0f + erff(x * INVSQRT2));
}

// ---------------------------------------------------------------- zero g
__global__ void zero_kernel(float* g) { g[threadIdx.x] = 0.0f; }

// ---------------------------------------------------------------- embed: h = relu(x@ew1+eb1)@ew2+eb2
__global__ __launch_bounds__(256) void embed_kernel(
    const float* __restrict__ x, const float* __restrict__ ew1, const float* __restrict__ eb1,
    const float* __restrict__ ew2, const float* __restrict__ eb2, float* __restrict__ h) {
  __shared__ float h1[4][DD];
  int w = threadIdx.x >> 6, c = threadIdx.x & 63;
  int pt = blockIdx.x * 4 + w;
  const float* xp = x + (size_t)pt * 3;
  float x0 = xp[0], x1 = xp[1], x2 = xp[2];
  float a = fmaf(x0, ew1[c], fmaf(x1, ew1[64 + c], fmaf(x2, ew1[128 + c], eb1[c])));
  h1[w][c] = fmaxf(a, 0.0f);
  __syncthreads();
  float s = eb2[c];
#pragma unroll 8
  for (int d = 0; d < DD; d++) s = fmaf(h1[w][d], ew2[d * 64 + c], s);
  h[(size_t)pt * 64 + c] = s;
}

// ---------------------------------------------------------------- knn: top-8 smallest d2 (stable ties)
__global__ __launch_bounds__(256) void knn_kernel(const float* __restrict__ x, int* __restrict__ idx) {
  __shared__ __attribute__((aligned(16))) float4 pp[NN];  // x,y,z,sq  -> 64KB
  int b = blockIdx.x >> 4;             // 16 blocks per batch
  int t = (blockIdx.x & 15) * 256 + threadIdx.x;
  const float* xb = x + (size_t)b * NN * 3;
  for (int j = threadIdx.x; j < NN; j += 256) {
    float a0 = xb[j * 3 + 0], a1 = xb[j * 3 + 1], a2 = xb[j * 3 + 2];
    pp[j] = make_float4(a0, a1, a2, a0 * a0 + a1 * a1 + a2 * a2);
  }
  __syncthreads();
  float4 qp = pp[t];
  float bd[8];
  int bi[8];
#pragma unroll
  for (int u = 0; u < 8; u++) { bd[u] = INFINITY; bi[u] = -1; }
  for (int j = 0; j < NN; j++) {
    float4 pj = pp[j];
    float dot = qp.x * pj.x + qp.y * pj.y + qp.z * pj.z;
    float d2 = qp.w - 2.0f * dot + pj.w;
    if (d2 < bd[7]) {                   // rare path
#pragma unroll
      for (int u = 7; u > 0; u--) {
        bool sh = d2 < bd[u - 1];
        float nd = sh ? bd[u - 1] : d2;
        int ni = sh ? bi[u - 1] : j;
        if (d2 < bd[u]) { bd[u] = nd; bi[u] = ni; }
      }
      if (d2 < bd[0]) { bd[0] = d2; bi[0] = j; }
    }
  }
  int* op = idx + ((size_t)b * NN + t) * 8;
#pragma unroll
  for (int u = 0; u < 8; u++) op[u] = bi[u];
}

// ---------------------------------------------------------------- qkv projection (4 points per wave)
__global__ __launch_bounds__(256) void qkv_kernel(
    const float* __restrict__ h, const float* __restrict__ wq, const float* __restrict__ bq,
    const float* __restrict__ wk, const float* __restrict__ bk,
    const float* __restrict__ wv, const float* __restrict__ bv,
    float* __restrict__ q, float* __restrict__ k, float* __restrict__ v) {
  __shared__ float lwq[DD * DD], lwk[DD * DD], lwv[DD * DD];
  __shared__ float lbq[DD], lbk[DD], lbv[DD];
  __shared__ __attribute__((aligned(16))) float hb[4][DD][4];
  int tid = threadIdx.x;
  for (int i = tid; i < DD * DD; i += 256) { lwq[i] = wq[i]; lwk[i] = wk[i]; lwv[i] = wv[i]; }
  if (tid < DD) { lbq[tid] = bq[tid]; lbk[tid] = bk[tid]; lbv[tid] = bv[tid]; }
  __syncthreads();
  int w = tid >> 6, c = tid & 63;
  constexpr int ITERS = (BB * NN) / (QKV_GRID * 16);
  for (int it = 0; it < ITERS; ++it) {
    int wid = it * (QKV_GRID * 4) + blockIdx.x * 4 + w;
    int p0 = wid * 4;
    __syncthreads();
#pragma unroll
    for (int i = 0; i < 4; i++) hb[w][c][i] = h[(size_t)(p0 + i) * 64 + c];
    __syncthreads();
    float aq[4], ak[4], av[4];
#pragma unroll
    for (int i = 0; i < 4; i++) { aq[i] = lbq[c]; ak[i] = lbk[c]; av[i] = lbv[c]; }
#pragma unroll 4
    for (int d = 0; d < DD; d++) {
      float wq_ = lwq[d * 64 + c], wk_ = lwk[d * 64 + c], wv_ = lwv[d * 64 + c];
      float4 hh = *(const float4*)&hb[w][d][0];
      aq[0] = fmaf(hh.x, wq_, aq[0]); aq[1] = fmaf(hh.y, wq_, aq[1]);
      aq[2] = fmaf(hh.z, wq_, aq[2]); aq[3] = fmaf(hh.w, wq_, aq[3]);
      ak[0] = fmaf(hh.x, wk_, ak[0]); ak[1] = fmaf(hh.y, wk_, ak[1]);
      ak[2] = fmaf(hh.z, wk_, ak[2]); ak[3] = fmaf(hh.w, wk_, ak[3]);
      av[0] = fmaf(hh.x, wv_, av[0]); av[1] = fmaf(hh.y, wv_, av[1]);
      av[2] = fmaf(hh.z, wv_, av[2]); av[3] = fmaf(hh.w, wv_, av[3]);
    }
#pragma unroll
    for (int i = 0; i < 4; i++) {
      q[(size_t)(p0 + i) * 64 + c] = aq[i];
      k[(size_t)(p0 + i) * 64 + c] = ak[i];
      v[(size_t)(p0 + i) * 64 + c] = av[i];
    }
  }
}

// ---------------------------------------------------------------- attention (1 point per wave) -> t = ln1(attn+x)
// NOTE: t may alias q (same-point read-then-write only) -> no __restrict__ on q/t.
__global__ __launch_bounds__(256) void attn_kernel(
    const float* __restrict__ x, const float* __restrict__ h,
    const float* q, const float* __restrict__ kk, const float* __restrict__ vv,
    const int* __restrict__ idx,
    const float* __restrict__ pw1, const float* __restrict__ pb1,
    const float* __restrict__ pw2, const float* __restrict__ pb2,
    const float* __restrict__ aw, const float* __restrict__ ab,
    const float* __restrict__ ow, const float* __restrict__ ob,
    const float* __restrict__ l1g, const float* __restrict__ l1b,
    float* t) {
  __shared__ float lpw2[DD * DD], low[DD * DD];
  __shared__ float lpw1[3 * DD], lpb1[DD], lpb2[DD], law[DD], lob[DD], ll1g[DD], ll1b[DD];
  __shared__ __attribute__((aligned(16))) float h1lo[4][DD][4], h1hi[4][DD][4];
  __shared__ __attribute__((aligned(16))) float outb[4][DD];
  int tid = threadIdx.x;
  for (int i = tid; i < DD * DD; i += 256) { lpw2[i] = pw2[i]; low[i] = ow[i]; }
  if (tid < 3 * DD) lpw1[tid] = pw1[tid];
  if (tid < DD) {
    lpb1[tid] = pb1[tid]; lpb2[tid] = pb2[tid]; law[tid] = aw[tid];
    lob[tid] = ob[tid]; ll1g[tid] = l1g[tid]; ll1b[tid] = l1b[tid];
  }
  float lab = ab[0];
  __syncthreads();
  int w = tid >> 6, c = tid & 63;
  constexpr int ITERS = (BB * NN) / (ATTN_GRID * 4);
  for (int it = 0; it < ITERS; ++it) {
    int p = (it * ATTN_GRID + blockIdx.x) * 4 + w;
    int b = p >> 12;
    int n = p & (NN - 1);
    const float* xb = x + (size_t)b * NN * 3;
    float hs = h[(size_t)p * 64 + c];
    float qs = q[(size_t)p * 64 + c];
    float px0 = xb[n * 3 + 0], px1 = xb[n * 3 + 1], px2 = xb[n * 3 + 2];
    int nb[8];
#pragma unroll
    for (int u = 0; u < 8; u++) nb[u] = idx[(size_t)p * 8 + u];
    __syncthreads();
#pragma unroll
    for (int u = 0; u < 8; u++) {
      int m = nb[u];
      float d0 = px0 - xb[m * 3 + 0], d1 = px1 - xb[m * 3 + 1], d2 = px2 - xb[m * 3 + 2];
      float h1 = fmaf(d0, lpw1[c], fmaf(d1, lpw1[64 + c], fmaf(d2, lpw1[128 + c], lpb1[c])));
      h1 = fmaxf(h1, 0.0f);
      if (u < 4) h1lo[w][c][u] = h1; else h1hi[w][c][u - 4] = h1;
    }
    __syncthreads();
    float acc[8];
#pragma unroll
    for (int u = 0; u < 8; u++) acc[u] = lpb2[c];
#pragma unroll 4
    for (int d = 0; d < DD; d++) {
      float wv_ = lpw2[d * 64 + c];
      float4 lo = *(const float4*)&h1lo[w][d][0];
      float4 hi = *(const float4*)&h1hi[w][d][0];
      acc[0] = fmaf(lo.x, wv_, acc[0]); acc[1] = fmaf(lo.y, wv_, acc[1]);
      acc[2] = fmaf(lo.z, wv_, acc[2]); acc[3] = fmaf(lo.w, wv_, acc[3]);
      acc[4] = fmaf(hi.x, wv_, acc[4]); acc[5] = fmaf(hi.y, wv_, acc[5]);
      acc[6] = fmaf(hi.z, wv_, acc[6]); acc[7] = fmaf(hi.w, wv_, acc[7]);
    }
    float lg[8];
#pragma unroll
    for (int u = 0; u < 8; u++) {
      float kv = kk[((size_t)(b << 12) + nb[u]) * 64 + c];
      float ai = qs - kv + acc[u];
      lg[u] = wave_sum(ai * law[c]) + lab;
    }
    float mx = lg[0];
#pragma unroll
    for (int u = 1; u < 8; u++) mx = fmaxf(mx, lg[u]);
    float ssum = 0.0f;
#pragma unroll
    for (int u = 0; u < 8; u++) { lg[u] = expf(lg[u] - mx); ssum += lg[u]; }
    float inv = 1.0f / ssum;
    float out = 0.0f;
#pragma unroll
    for (int u = 0; u < 8; u++) {
      float vg = vv[((size_t)(b << 12) + nb[u]) * 64 + c];
      out = fmaf(lg[u] * inv, vg + acc[u], out);
    }
    outb[w][c] = out;
    __syncthreads();
    float at = lob[c];
#pragma unroll 4
    for (int d = 0; d < DD; d += 4) {
      float4 ov = *(const float4*)&outb[w][d];
      at = fmaf(ov.x, low[(d + 0) * 64 + c], at);
      at = fmaf(ov.y, low[(d + 1) * 64 + c], at);
      at = fmaf(ov.z, low[(d + 2) * 64 + c], at);
      at = fmaf(ov.w, low[(d + 3) * 64 + c], at);
    }
    float res = at + hs;
    float mean = wave_sum(res) * (1.0f / 64.0f);
    float dv = res - mean;
    float var = wave_sum(dv * dv) * (1.0f / 64.0f);
    float ivr = 1.0f / sqrtf(var + LNEPS);
    t[(size_t)p * 64 + c] = fmaf(ll1g[c], dv * ivr, ll1b[c]);
  }
}

// ---------------------------------------------------------------- ffn (4 points per wave) -> h = ln2(t + ffn(t))
__global__ __launch_bounds__(256) void ffn_kernel(
    const float* __restrict__ t, const float* __restrict__ fw1, const float* __restrict__ fb1,
    const float* __restrict__ fw2, const float* __restrict__ fb2,
    const float* __restrict__ l2g, const float* __restrict__ l2b, float* __restrict__ h) {
  __shared__ float lf1[DD * 128];
  __shared__ float lf2[128 * DD];
  __shared__ float lb1[128], lb2[DD], lg2[DD], lbt2[DD];
  __shared__ __attribute__((aligned(16))) float yb[4][DD][4];
  __shared__ __attribute__((aligned(16))) float hb[4][128][4];
  int tid = threadIdx.x;
  for (int i = tid; i < DD * 128; i += 256) { lf1[i] = fw1[i]; lf2[i] = fw2[i]; }
  if (tid < 128) lb1[tid] = fb1[tid];
  if (tid < DD) { lb2[tid] = fb2[tid]; lg2[tid] = l2g[tid]; lbt2[tid] = l2b[tid]; }
  __syncthreads();
  int w = tid >> 6, c = tid & 63;
  constexpr int ITERS = (BB * NN) / (FFN_GRID * 16);
  for (int it = 0; it < ITERS; ++it) {
    int wid = it * (FFN_GRID * 4) + blockIdx.x * 4 + w;
    int p0 = wid * 4;
    float y[4];
    __syncthreads();
#pragma unroll
    for (int i = 0; i < 4; i++) { y[i] = t[(size_t)(p0 + i) * 64 + c]; yb[w][c][i] = y[i]; }
    __syncthreads();
    float hA[4], hB[4];
#pragma unroll
    for (int i = 0; i < 4; i++) { hA[i] = lb1[c]; hB[i] = lb1[64 + c]; }
#pragma unroll 4
    for (int d = 0; d < DD; d++) {
      float w0 = lf1[d * 128 + c], w1 = lf1[d * 128 + 64 + c];
      float4 yv = *(const float4*)&yb[w][d][0];
      hA[0] = fmaf(yv.x, w0, hA[0]); hA[1] = fmaf(yv.y, w0, hA[1]);
      hA[2] = fmaf(yv.z, w0, hA[2]); hA[3] = fmaf(yv.w, w0, hA[3]);
      hB[0] = fmaf(yv.x, w1, hB[0]); hB[1] = fmaf(yv.y, w1, hB[1]);
      hB[2] = fmaf(yv.z, w1, hB[2]); hB[3] = fmaf(yv.w, w1, hB[3]);
    }
#pragma unroll
    for (int i = 0; i < 4; i++) {
      hA[i] = gelu_exact(hA[i]); hB[i] = gelu_exact(hB[i]);
      hb[w][c][i] = hA[i]; hb[w][64 + c][i] = hB[i];
    }
    __syncthreads();
    float o[4];
#pragma unroll
    for (int i = 0; i < 4; i++) o[i] = lb2[c];
#pragma unroll 4
    for (int j = 0; j < 128; j++) {
      float wv_ = lf2[j * 64 + c];
      float4 hv = *(const float4*)&hb[w][j][0];
      o[0] = fmaf(hv.x, wv_, o[0]); o[1] = fmaf(hv.y, wv_, o[1]);
      o[2] = fmaf(hv.z, wv_, o[2]); o[3] = fmaf(hv.w, wv_, o[3]);
    }
#pragma unroll
    for (int i = 0; i < 4; i++) {
      float r = y[i] + o[i];
      float mean = wave_sum(r) * (1.0f / 64.0f);
      float dv = r - mean;
      float var = wave_sum(dv * dv) * (1.0f / 64.0f);
      float ivr = 1.0f / sqrtf(var + LNEPS);
      h[(size_t)(p0 + i) * 64 + c] = fmaf(lg2[c], dv * ivr, lbt2[c]);
    }
  }
}

// ---------------------------------------------------------------- classifier proj + blockwise max-pool
__global__ __launch_bounds__(256) void cls_kernel(
    const float* __restrict__ h, const float* __restrict__ cw, const float* __restrict__ cb,
    const float* __restrict__ cg, const float* __restrict__ cbeta, float* __restrict__ g) {
  __shared__ float lcw[DD * 128];
  __shared__ float lcb[128], lcg[128], lcbt[128];
  __shared__ __attribute__((aligned(16))) float hb[4][DD][4];
  __shared__ float wmax[4][128];
  int tid = threadIdx.x;
  for (int i = tid; i < DD * 128; i += 256) lcw[i] = cw[i];
  if (tid < 128) { lcb[tid] = cb[tid]; lcg[tid] = cg[tid]; lcbt[tid] = cbeta[tid]; }
  __syncthreads();
  int w = tid >> 6, c = tid & 63;
  int b = blockIdx.x >> 7;            // 128 blocks per batch
  int blk = blockIdx.x & 127;
  int base = b * NN + blk * 32;
  float m0 = 0.0f, m1 = 0.0f;
  for (int it = 0; it < 2; ++it) {
    int p0 = base + (w * 2 + it) * 4;
    __syncthreads();
#pragma unroll
    for (int i = 0; i < 4; i++) hb[w][c][i] = h[(size_t)(p0 + i) * 64 + c];
    __syncthreads();
    float a0[4], a1[4];
#pragma unroll
    for (int i = 0; i < 4; i++) { a0[i] = lcb[c]; a1[i] = lcb[64 + c]; }
#pragma unroll 4
    for (int d = 0; d < DD; d++) {
      float w0 = lcw[d * 128 + c], w1 = lcw[d * 128 + 64 + c];
      float4 hv = *(const float4*)&hb[w][d][0];
      a0[0] = fmaf(hv.x, w0, a0[0]); a0[1] = fmaf(hv.y, w0, a0[1]);
      a0[2] = fmaf(hv.z, w0, a0[2]); a0[3] = fmaf(hv.w, w0, a0[3]);
      a1[0] = fmaf(hv.x, w1, a1[0]); a1[1] = fmaf(hv.y, w1, a1[1]);
      a1[2] = fmaf(hv.z, w1, a1[2]); a1[3] = fmaf(hv.w, w1, a1[3]);
    }
#pragma unroll
    for (int i = 0; i < 4; i++) {
      m0 = fmaxf(m0, fmaxf(0.0f, fmaf(lcg[c] * a0[i], BNRS, lcbt[c])));
      m1 = fmaxf(m1, fmaxf(0.0f, fmaf(lcg[64 + c] * a1[i], BNRS, lcbt[64 + c])));
    }
  }
  wmax[w][c] = m0; wmax[w][64 + c] = m1;
  __syncthreads();
  if (tid < 128) {
    float mm = fmaxf(fmaxf(wmax[0][tid], wmax[1][tid]), fmaxf(wmax[2][tid], wmax[3][tid]));
    atomicMax((int*)&g[b * 128 + tid], __float_as_int(mm));  // values >= 0
  }
}

// ---------------------------------------------------------------- final head (per batch)
__global__ __launch_bounds__(128) void head_kernel(
    const float* __restrict__ g,
    const float* __restrict__ f1w, const float* __restrict__ f1b,
    const float* __restrict__ b1g, const float* __restrict__ b1b,
    const float* __restrict__ f2w, const float* __restrict__ f2b,
    const float* __restrict__ b2g, const float* __restrict__ b2b,
    const float* __restrict__ f3w, const float* __restrict__ f3b,
    float* __restrict__ out) {
  __shared__ float gb[128], g1[128], g2[64];
  int b = blockIdx.x, t = threadIdx.x;
  gb[t] = g[b * 128 + t];
  __syncthreads();
  float a = f1b[t];
#pragma unroll 4
  for (int d = 0; d < 128; d++) a = fmaf(gb[d], f1w[d * 128 + t], a);
  g1[t] = fmaxf(0.0f, fmaf(b1g[t] * a, BNRS, b1b[t]));
  __syncthreads();
  if (t < 64) {
    float a2 = f2b[t];
#pragma unroll 4
    for (int j = 0; j < 128; j++) a2 = fmaf(g1[j], f2w[j * 64 + t], a2);
    g2[t] = fmaxf(0.0f, fmaf(b2g[t] * a2, BNRS, b2b[t]));
  }
  __syncthreads();
  if (t < NCLS) {
    float a3 = f3b[t];
#pragma unroll
    for (int d = 0; d < 64; d++) a3 = fmaf(g2[d], f3w[d * NCLS + t], a3);
    out[b * NCLS + t] = a3;
  }
}

extern "C" void kernel_launch(void* const* d_in, const int* in_sizes, int n_in,
                              void* d_out, int out_size, void* d_ws, size_t ws_size,
                              hipStream_t stream) {
  const float* x    = (const float*)d_in[0];
  const float* ew1  = (const float*)d_in[1];
  const float* eb1  = (const float*)d_in[2];
  const float* ew2  = (const float*)d_in[3];
  const float* eb2  = (const float*)d_in[4];
  const float* wq   = (const float*)d_in[5];
  const float* bq   = (const float*)d_in[6];
  const float* wk   = (const float*)d_in[7];
  const float* bk   = (const float*)d_in[8];
  const float* wv   = (const float*)d_in[9];
  const float* bv   = (const float*)d_in[10];
  const float* pw1  = (const float*)d_in[11];
  const float* pb1  = (const float*)d_in[12];
  const float* pw2  = (const float*)d_in[13];
  const float* pb2  = (const float*)d_in[14];
  const float* aw   = (const float*)d_in[15];
  const float* ab   = (const float*)d_in[16];
  const float* ow   = (const float*)d_in[17];
  const float* ob   = (const float*)d_in[18];
  const float* l1g  = (const float*)d_in[19];
  const float* l1b  = (const float*)d_in[20];
  const float* l2g  = (const float*)d_in[21];
  const float* l2b  = (const float*)d_in[22];
  const float* fw1  = (const float*)d_in[23];
  const float* fb1  = (const float*)d_in[24];
  const float* fw2  = (const float*)d_in[25];
  const float* fb2  = (const float*)d_in[26];
  const float* cw   = (const float*)d_in[27];
  const float* cb   = (const float*)d_in[28];
  const float* cg   = (const float*)d_in[29];
  const float* cbeta= (const float*)d_in[30];
  const float* f1w  = (const float*)d_in[31];
  const float* f1b  = (const float*)d_in[32];
  const float* b1g  = (const float*)d_in[33];
  const float* b1b  = (const float*)d_in[34];
  const float* f2w  = (const float*)d_in[35];
  const float* f2b  = (const float*)d_in[36];
  const float* b2g  = (const float*)d_in[37];
  const float* b2b  = (const float*)d_in[38];
  const float* f3w  = (const float*)d_in[39];
  const float* f3b  = (const float*)d_in[40];

  const size_t P = (size_t)BB * NN;       // 32768 points
  float* ws = (float*)d_ws;
  float* h = ws;                          // P*64
  float* q = h + P * 64;
  float* k = q + P * 64;
  float* v = k + P * 64;
  int* idx = (int*)(v + P * 64);          // P*8 ints
  float* g = (float*)(idx + P * 8);       // B*128
  float* t = q;                           // alias: safe (same-point read-then-write)

  zero_kernel<<<1, BB * 128, 0, stream>>>(g);
  embed_kernel<<<(int)(P / 4), 256, 0, stream>>>(x, ew1, eb1, ew2, eb2, h);
  knn_kernel<<<BB * 16, 256, 0, stream>>>(x, idx);
  for (int l = 0; l < 2; l++) {
    qkv_kernel<<<QKV_GRID, 256, 0, stream>>>(h, wq + l * DD * DD, bq + l * DD,
                                             wk + l * DD * DD, bk + l * DD,
                                             wv + l * DD * DD, bv + l * DD, q, k, v);
    attn_kernel<<<ATTN_GRID, 256, 0, stream>>>(x, h, q, k, v, idx,
                                               pw1 + l * 3 * DD, pb1 + l * DD,
                                               pw2 + l * DD * DD, pb2 + l * DD,
                                               aw + l * DD, ab + l,
                                               ow + l * DD * DD, ob + l * DD,
                                               l1g + l * DD, l1b + l * DD, t);
    ffn_kernel<<<FFN_GRID, 256, 0, stream>>>(t, fw1 + l * DD * 2 * DD, fb1 + l * 2 * DD,
                                             fw2 + l * 2 * DD * DD, fb2 + l * DD,
                                             l2g + l * DD, l2b + l * DD, h);
  }
  cls_kernel<<<BB * 128, 256, 0, stream>>>(h, cw, cb, cg, cbeta, g);
  head_kernel<<<BB, 128, 0, stream>>>(g, f1w, f1b, b1g, b1b, f2w, f2b, b2g, b2b, f3w, f3b,
                                      (float*)d_out);
}

// Round 3
// 536.683 us; speedup vs baseline: 1.5963x; 1.5963x over previous
//
#include <hip/hip_runtime.h>
#include <cmath>

#define BB 8
#define NN 4096
#define DD 64
#define KK 8
#define NCLS 2

constexpr float LNEPS = 1e-5f;
constexpr float BNRS = 0.9999950000374994f;      // 1/sqrt(1+1e-5)
constexpr float INVSQRT2 = 0.70710678118654752440f;

constexpr int QKV_GRID = 512;
constexpr int ATTN_GRID = 1024;
constexpr int FFN_GRID = 512;

// knn decomposition: 64 queries/block x 4 candidate-splits (one per wave)
#define QPB 64
#define SPLITS 4

__device__ __forceinline__ float wave_sum(float v) {
#pragma unroll
  for (int m = 32; m > 0; m >>= 1) v += __shfl_xor(v, m, 64);
  return v;
}

__device__ __forceinline__ float gelu_exact(float x) {
  return 0.5f * x * (1.0f + erff(x * INVSQRT2));
}

// ---------------------------------------------------------------- zero g
__global__ void zero_kernel(float* g) { g[threadIdx.x] = 0.0f; }

// ---------------------------------------------------------------- embed: h = relu(x@ew1+eb1)@ew2+eb2
__global__ __launch_bounds__(256) void embed_kernel(
    const float* __restrict__ x, const float* __restrict__ ew1, const float* __restrict__ eb1,
    const float* __restrict__ ew2, const float* __restrict__ eb2, float* __restrict__ h) {
  __shared__ float h1[4][DD];
  int w = threadIdx.x >> 6, c = threadIdx.x & 63;
  int pt = blockIdx.x * 4 + w;
  const float* xp = x + (size_t)pt * 3;
  float x0 = xp[0], x1 = xp[1], x2 = xp[2];
  float a = fmaf(x0, ew1[c], fmaf(x1, ew1[64 + c], fmaf(x2, ew1[128 + c], eb1[c])));
  h1[w][c] = fmaxf(a, 0.0f);
  __syncthreads();
  float s = eb2[c];
#pragma unroll 8
  for (int d = 0; d < DD; d++) s = fmaf(h1[w][d], ew2[d * 64 + c], s);
  h[(size_t)pt * 64 + c] = s;
}

// ---------------------------------------------------------------- knn: top-8 smallest d2 (stable ties)
// 512 blocks: 64 queries/block, candidate range split 4-way across waves,
// partial top-8 lists merged (stably) by wave 0.
__global__ __launch_bounds__(256) void knn_kernel(const float* __restrict__ x, int* __restrict__ idx) {
  __shared__ __attribute__((aligned(16))) float4 pp[NN];        // 64KB: x,y,z,|p|^2
  __shared__ float2 mb[SPLITS * 8][QPB];                        // 16KB, transposed for conflict-free access
  int b = blockIdx.x >> 6;                                      // 64 blocks per batch
  int qbase = (blockIdx.x & 63) * QPB;
  const float* xb = x + (size_t)b * NN * 3;
  for (int j = threadIdx.x; j < NN; j += 256) {
    float a0 = xb[j * 3 + 0], a1 = xb[j * 3 + 1], a2 = xb[j * 3 + 2];
    pp[j] = make_float4(a0, a1, a2, a0 * a0 + a1 * a1 + a2 * a2);
  }
  __syncthreads();
  int ql = threadIdx.x & 63;
  int sp = threadIdx.x >> 6;                                    // split id == wave id (uniform pp[j] reads)
  float4 qp = pp[qbase + ql];
  float bd[8];
  int bi[8];
#pragma unroll
  for (int u = 0; u < 8; u++) { bd[u] = INFINITY; bi[u] = -1; }
  int j0 = sp * (NN / SPLITS);
#pragma unroll 2
  for (int jj = 0; jj < NN / SPLITS; jj++) {
    int j = j0 + jj;
    float4 pj = pp[j];
    float dot = qp.x * pj.x + qp.y * pj.y + qp.z * pj.z;
    float d2 = qp.w - 2.0f * dot + pj.w;
    if (d2 < bd[7]) {                   // rare path
#pragma unroll
      for (int u = 7; u > 0; u--) {
        bool sh = d2 < bd[u - 1];
        float nd = sh ? bd[u - 1] : d2;
        int ni = sh ? bi[u - 1] : j;
        if (d2 < bd[u]) { bd[u] = nd; bi[u] = ni; }
      }
      if (d2 < bd[0]) { bd[0] = d2; bi[0] = j; }
    }
  }
  // publish sorted partial lists (entry order = split-major, index-stable)
#pragma unroll
  for (int u = 0; u < 8; u++) mb[sp * 8 + u][ql] = make_float2(bd[u], __int_as_float(bi[u]));
  __syncthreads();
  if (threadIdx.x < QPB) {
    int qq = threadIdx.x;
    float cd[8];
    int ci[8];
#pragma unroll
    for (int u = 0; u < 8; u++) { cd[u] = INFINITY; ci[u] = -1; }
    for (int e = 0; e < SPLITS * 8; e++) {
      float2 ent = mb[e][qq];
      float d2 = ent.x;
      int ji = __float_as_int(ent.y);
      if (d2 < cd[7]) {
#pragma unroll
        for (int u = 7; u > 0; u--) {
          bool sh = d2 < cd[u - 1];
          float nd = sh ? cd[u - 1] : d2;
          int ni = sh ? ci[u - 1] : ji;
          if (d2 < cd[u]) { cd[u] = nd; ci[u] = ni; }
        }
        if (d2 < cd[0]) { cd[0] = d2; ci[0] = ji; }
      }
    }
    int* op = idx + ((size_t)b * NN + qbase + qq) * 8;
#pragma unroll
    for (int u = 0; u < 8; u++) op[u] = ci[u];
  }
}

// ---------------------------------------------------------------- qkv projection (4 points per wave)
__global__ __launch_bounds__(256) void qkv_kernel(
    const float* __restrict__ h, const float* __restrict__ wq, const float* __restrict__ bq,
    const float* __restrict__ wk, const float* __restrict__ bk,
    const float* __restrict__ wv, const float* __restrict__ bv,
    float* __restrict__ q, float* __restrict__ k, float* __restrict__ v) {
  __shared__ float lwq[DD * DD], lwk[DD * DD], lwv[DD * DD];
  __shared__ float lbq[DD], lbk[DD], lbv[DD];
  __shared__ __attribute__((aligned(16))) float hb[4][DD][4];
  int tid = threadIdx.x;
  for (int i = tid; i < DD * DD; i += 256) { lwq[i] = wq[i]; lwk[i] = wk[i]; lwv[i] = wv[i]; }
  if (tid < DD) { lbq[tid] = bq[tid]; lbk[tid] = bk[tid]; lbv[tid] = bv[tid]; }
  __syncthreads();
  int w = tid >> 6, c = tid & 63;
  constexpr int ITERS = (BB * NN) / (QKV_GRID * 16);
  for (int it = 0; it < ITERS; ++it) {
    int wid = it * (QKV_GRID * 4) + blockIdx.x * 4 + w;
    int p0 = wid * 4;
    __syncthreads();
#pragma unroll
    for (int i = 0; i < 4; i++) hb[w][c][i] = h[(size_t)(p0 + i) * 64 + c];
    __syncthreads();
    float aq[4], ak[4], av[4];
#pragma unroll
    for (int i = 0; i < 4; i++) { aq[i] = lbq[c]; ak[i] = lbk[c]; av[i] = lbv[c]; }
#pragma unroll 4
    for (int d = 0; d < DD; d++) {
      float wq_ = lwq[d * 64 + c], wk_ = lwk[d * 64 + c], wv_ = lwv[d * 64 + c];
      float4 hh = *(const float4*)&hb[w][d][0];
      aq[0] = fmaf(hh.x, wq_, aq[0]); aq[1] = fmaf(hh.y, wq_, aq[1]);
      aq[2] = fmaf(hh.z, wq_, aq[2]); aq[3] = fmaf(hh.w, wq_, aq[3]);
      ak[0] = fmaf(hh.x, wk_, ak[0]); ak[1] = fmaf(hh.y, wk_, ak[1]);
      ak[2] = fmaf(hh.z, wk_, ak[2]); ak[3] = fmaf(hh.w, wk_, ak[3]);
      av[0] = fmaf(hh.x, wv_, av[0]); av[1] = fmaf(hh.y, wv_, av[1]);
      av[2] = fmaf(hh.z, wv_, av[2]); av[3] = fmaf(hh.w, wv_, av[3]);
    }
#pragma unroll
    for (int i = 0; i < 4; i++) {
      q[(size_t)(p0 + i) * 64 + c] = aq[i];
      k[(size_t)(p0 + i) * 64 + c] = ak[i];
      v[(size_t)(p0 + i) * 64 + c] = av[i];
    }
  }
}

// ---------------------------------------------------------------- attention (1 point per wave) -> t = ln1(attn+x)
// NOTE: t may alias q (same-point read-then-write only) -> no __restrict__ on q/t.
__global__ __launch_bounds__(256) void attn_kernel(
    const float* __restrict__ x, const float* __restrict__ h,
    const float* q, const float* __restrict__ kk, const float* __restrict__ vv,
    const int* __restrict__ idx,
    const float* __restrict__ pw1, const float* __restrict__ pb1,
    const float* __restrict__ pw2, const float* __restrict__ pb2,
    const float* __restrict__ aw, const float* __restrict__ ab,
    const float* __restrict__ ow, const float* __restrict__ ob,
    const float* __restrict__ l1g, const float* __restrict__ l1b,
    float* t) {
  __shared__ float lpw2[DD * DD], low[DD * DD];
  __shared__ float lpw1[3 * DD], lpb1[DD], lpb2[DD], law[DD], lob[DD], ll1g[DD], ll1b[DD];
  __shared__ __attribute__((aligned(16))) float h1lo[4][DD][4], h1hi[4][DD][4];
  __shared__ __attribute__((aligned(16))) float outb[4][DD];
  int tid = threadIdx.x;
  for (int i = tid; i < DD * DD; i += 256) { lpw2[i] = pw2[i]; low[i] = ow[i]; }
  if (tid < 3 * DD) lpw1[tid] = pw1[tid];
  if (tid < DD) {
    lpb1[tid] = pb1[tid]; lpb2[tid] = pb2[tid]; law[tid] = aw[tid];
    lob[tid] = ob[tid]; ll1g[tid] = l1g[tid]; ll1b[tid] = l1b[tid];
  }
  float lab = ab[0];
  __syncthreads();
  int w = tid >> 6, c = tid & 63;
  constexpr int ITERS = (BB * NN) / (ATTN_GRID * 4);
  for (int it = 0; it < ITERS; ++it) {
    int p = (it * ATTN_GRID + blockIdx.x) * 4 + w;
    int b = p >> 12;
    int n = p & (NN - 1);
    const float* xb = x + (size_t)b * NN * 3;
    float hs = h[(size_t)p * 64 + c];
    float qs = q[(size_t)p * 64 + c];
    float px0 = xb[n * 3 + 0], px1 = xb[n * 3 + 1], px2 = xb[n * 3 + 2];
    int nb[8];
#pragma unroll
    for (int u = 0; u < 8; u++) nb[u] = idx[(size_t)p * 8 + u];
    __syncthreads();
#pragma unroll
    for (int u = 0; u < 8; u++) {
      int m = nb[u];
      float d0 = px0 - xb[m * 3 + 0], d1 = px1 - xb[m * 3 + 1], d2 = px2 - xb[m * 3 + 2];
      float h1 = fmaf(d0, lpw1[c], fmaf(d1, lpw1[64 + c], fmaf(d2, lpw1[128 + c], lpb1[c])));
      h1 = fmaxf(h1, 0.0f);
      if (u < 4) h1lo[w][c][u] = h1; else h1hi[w][c][u - 4] = h1;
    }
    __syncthreads();
    float acc[8];
#pragma unroll
    for (int u = 0; u < 8; u++) acc[u] = lpb2[c];
#pragma unroll 4
    for (int d = 0; d < DD; d++) {
      float wv_ = lpw2[d * 64 + c];
      float4 lo = *(const float4*)&h1lo[w][d][0];
      float4 hi = *(const float4*)&h1hi[w][d][0];
      acc[0] = fmaf(lo.x, wv_, acc[0]); acc[1] = fmaf(lo.y, wv_, acc[1]);
      acc[2] = fmaf(lo.z, wv_, acc[2]); acc[3] = fmaf(lo.w, wv_, acc[3]);
      acc[4] = fmaf(hi.x, wv_, acc[4]); acc[5] = fmaf(hi.y, wv_, acc[5]);
      acc[6] = fmaf(hi.z, wv_, acc[6]); acc[7] = fmaf(hi.w, wv_, acc[7]);
    }
    float lg[8];
#pragma unroll
    for (int u = 0; u < 8; u++) {
      float kv = kk[((size_t)(b << 12) + nb[u]) * 64 + c];
      float ai = qs - kv + acc[u];
      lg[u] = wave_sum(ai * law[c]) + lab;
    }
    float mx = lg[0];
#pragma unroll
    for (int u = 1; u < 8; u++) mx = fmaxf(mx, lg[u]);
    float ssum = 0.0f;
#pragma unroll
    for (int u = 0; u < 8; u++) { lg[u] = expf(lg[u] - mx); ssum += lg[u]; }
    float inv = 1.0f / ssum;
    float out = 0.0f;
#pragma unroll
    for (int u = 0; u < 8; u++) {
      float vg = vv[((size_t)(b << 12) + nb[u]) * 64 + c];
      out = fmaf(lg[u] * inv, vg + acc[u], out);
    }
    outb[w][c] = out;
    __syncthreads();
    float at = lob[c];
#pragma unroll 4
    for (int d = 0; d < DD; d += 4) {
      float4 ov = *(const float4*)&outb[w][d];
      at = fmaf(ov.x, low[(d + 0) * 64 + c], at);
      at = fmaf(ov.y, low[(d + 1) * 64 + c], at);
      at = fmaf(ov.z, low[(d + 2) * 64 + c], at);
      at = fmaf(ov.w, low[(d + 3) * 64 + c], at);
    }
    float res = at + hs;
    float mean = wave_sum(res) * (1.0f / 64.0f);
    float dv = res - mean;
    float var = wave_sum(dv * dv) * (1.0f / 64.0f);
    float ivr = 1.0f / sqrtf(var + LNEPS);
    t[(size_t)p * 64 + c] = fmaf(ll1g[c], dv * ivr, ll1b[c]);
  }
}

// ---------------------------------------------------------------- ffn (4 points per wave) -> h = ln2(t + ffn(t))
__global__ __launch_bounds__(256) void ffn_kernel(
    const float* __restrict__ t, const float* __restrict__ fw1, const float* __restrict__ fb1,
    const float* __restrict__ fw2, const float* __restrict__ fb2,
    const float* __restrict__ l2g, const float* __restrict__ l2b, float* __restrict__ h) {
  __shared__ float lf1[DD * 128];
  __shared__ float lf2[128 * DD];
  __shared__ float lb1[128], lb2[DD], lg2[DD], lbt2[DD];
  __shared__ __attribute__((aligned(16))) float yb[4][DD][4];
  __shared__ __attribute__((aligned(16))) float hb[4][128][4];
  int tid = threadIdx.x;
  for (int i = tid; i < DD * 128; i += 256) { lf1[i] = fw1[i]; lf2[i] = fw2[i]; }
  if (tid < 128) lb1[tid] = fb1[tid];
  if (tid < DD) { lb2[tid] = fb2[tid]; lg2[tid] = l2g[tid]; lbt2[tid] = l2b[tid]; }
  __syncthreads();
  int w = tid >> 6, c = tid & 63;
  constexpr int ITERS = (BB * NN) / (FFN_GRID * 16);
  for (int it = 0; it < ITERS; ++it) {
    int wid = it * (FFN_GRID * 4) + blockIdx.x * 4 + w;
    int p0 = wid * 4;
    float y[4];
    __syncthreads();
#pragma unroll
    for (int i = 0; i < 4; i++) { y[i] = t[(size_t)(p0 + i) * 64 + c]; yb[w][c][i] = y[i]; }
    __syncthreads();
    float hA[4], hB[4];
#pragma unroll
    for (int i = 0; i < 4; i++) { hA[i] = lb1[c]; hB[i] = lb1[64 + c]; }
#pragma unroll 4
    for (int d = 0; d < DD; d++) {
      float w0 = lf1[d * 128 + c], w1 = lf1[d * 128 + 64 + c];
      float4 yv = *(const float4*)&yb[w][d][0];
      hA[0] = fmaf(yv.x, w0, hA[0]); hA[1] = fmaf(yv.y, w0, hA[1]);
      hA[2] = fmaf(yv.z, w0, hA[2]); hA[3] = fmaf(yv.w, w0, hA[3]);
      hB[0] = fmaf(yv.x, w1, hB[0]); hB[1] = fmaf(yv.y, w1, hB[1]);
      hB[2] = fmaf(yv.z, w1, hB[2]); hB[3] = fmaf(yv.w, w1, hB[3]);
    }
#pragma unroll
    for (int i = 0; i < 4; i++) {
      hA[i] = gelu_exact(hA[i]); hB[i] = gelu_exact(hB[i]);
      hb[w][c][i] = hA[i]; hb[w][64 + c][i] = hB[i];
    }
    __syncthreads();
    float o[4];
#pragma unroll
    for (int i = 0; i < 4; i++) o[i] = lb2[c];
#pragma unroll 4
    for (int j = 0; j < 128; j++) {
      float wv_ = lf2[j * 64 + c];
      float4 hv = *(const float4*)&hb[w][j][0];
      o[0] = fmaf(hv.x, wv_, o[0]); o[1] = fmaf(hv.y, wv_, o[1]);
      o[2] = fmaf(hv.z, wv_, o[2]); o[3] = fmaf(hv.w, wv_, o[3]);
    }
#pragma unroll
    for (int i = 0; i < 4; i++) {
      float r = y[i] + o[i];
      float mean = wave_sum(r) * (1.0f / 64.0f);
      float dv = r - mean;
      float var = wave_sum(dv * dv) * (1.0f / 64.0f);
      float ivr = 1.0f / sqrtf(var + LNEPS);
      h[(size_t)(p0 + i) * 64 + c] = fmaf(lg2[c], dv * ivr, lbt2[c]);
    }
  }
}

// ---------------------------------------------------------------- classifier proj + blockwise max-pool
__global__ __launch_bounds__(256) void cls_kernel(
    const float* __restrict__ h, const float* __restrict__ cw, const float* __restrict__ cb,
    const float* __restrict__ cg, const float* __restrict__ cbeta, float* __restrict__ g) {
  __shared__ float lcw[DD * 128];
  __shared__ float lcb[128], lcg[128], lcbt[128];
  __shared__ __attribute__((aligned(16))) float hb[4][DD][4];
  __shared__ float wmax[4][128];
  int tid = threadIdx.x;
  for (int i = tid; i < DD * 128; i += 256) lcw[i] = cw[i];
  if (tid < 128) { lcb[tid] = cb[tid]; lcg[tid] = cg[tid]; lcbt[tid] = cbeta[tid]; }
  __syncthreads();
  int w = tid >> 6, c = tid & 63;
  int b = blockIdx.x >> 7;            // 128 blocks per batch
  int blk = blockIdx.x & 127;
  int base = b * NN + blk * 32;
  float m0 = 0.0f, m1 = 0.0f;
  for (int it = 0; it < 2; ++it) {
    int p0 = base + (w * 2 + it) * 4;
    __syncthreads();
#pragma unroll
    for (int i = 0; i < 4; i++) hb[w][c][i] = h[(size_t)(p0 + i) * 64 + c];
    __syncthreads();
    float a0[4], a1[4];
#pragma unroll
    for (int i = 0; i < 4; i++) { a0[i] = lcb[c]; a1[i] = lcb[64 + c]; }
#pragma unroll 4
    for (int d = 0; d < DD; d++) {
      float w0 = lcw[d * 128 + c], w1 = lcw[d * 128 + 64 + c];
      float4 hv = *(const float4*)&hb[w][d][0];
      a0[0] = fmaf(hv.x, w0, a0[0]); a0[1] = fmaf(hv.y, w0, a0[1]);
      a0[2] = fmaf(hv.z, w0, a0[2]); a0[3] = fmaf(hv.w, w0, a0[3]);
      a1[0] = fmaf(hv.x, w1, a1[0]); a1[1] = fmaf(hv.y, w1, a1[1]);
      a1[2] = fmaf(hv.z, w1, a1[2]); a1[3] = fmaf(hv.w, w1, a1[3]);
    }
#pragma unroll
    for (int i = 0; i < 4; i++) {
      m0 = fmaxf(m0, fmaxf(0.0f, fmaf(lcg[c] * a0[i], BNRS, lcbt[c])));
      m1 = fmaxf(m1, fmaxf(0.0f, fmaf(lcg[64 + c] * a1[i], BNRS, lcbt[64 + c])));
    }
  }
  wmax[w][c] = m0; wmax[w][64 + c] = m1;
  __syncthreads();
  if (tid < 128) {
    float mm = fmaxf(fmaxf(wmax[0][tid], wmax[1][tid]), fmaxf(wmax[2][tid], wmax[3][tid]));
    atomicMax((int*)&g[b * 128 + tid], __float_as_int(mm));  // values >= 0
  }
}

// ---------------------------------------------------------------- final head (per batch)
__global__ __launch_bounds__(128) void head_kernel(
    const float* __restrict__ g,
    const float* __restrict__ f1w, const float* __restrict__ f1b,
    const float* __restrict__ b1g, const float* __restrict__ b1b,
    const float* __restrict__ f2w, const float* __restrict__ f2b,
    const float* __restrict__ b2g, const float* __restrict__ b2b,
    const float* __restrict__ f3w, const float* __restrict__ f3b,
    float* __restrict__ out) {
  __shared__ float gb[128], g1[128], g2[64];
  int b = blockIdx.x, t = threadIdx.x;
  gb[t] = g[b * 128 + t];
  __syncthreads();
  float a = f1b[t];
#pragma unroll 4
  for (int d = 0; d < 128; d++) a = fmaf(gb[d], f1w[d * 128 + t], a);
  g1[t] = fmaxf(0.0f, fmaf(b1g[t] * a, BNRS, b1b[t]));
  __syncthreads();
  if (t < 64) {
    float a2 = f2b[t];
#pragma unroll 4
    for (int j = 0; j < 128; j++) a2 = fmaf(g1[j], f2w[j * 64 + t], a2);
    g2[t] = fmaxf(0.0f, fmaf(b2g[t] * a2, BNRS, b2b[t]));
  }
  __syncthreads();
  if (t < NCLS) {
    float a3 = f3b[t];
#pragma unroll
    for (int d = 0; d < 64; d++) a3 = fmaf(g2[d], f3w[d * NCLS + t], a3);
    out[b * NCLS + t] = a3;
  }
}

extern "C" void kernel_launch(void* const* d_in, const int* in_sizes, int n_in,
                              void* d_out, int out_size, void* d_ws, size_t ws_size,
                              hipStream_t stream) {
  const float* x    = (const float*)d_in[0];
  const float* ew1  = (const float*)d_in[1];
  const float* eb1  = (const float*)d_in[2];
  const float* ew2  = (const float*)d_in[3];
  const float* eb2  = (const float*)d_in[4];
  const float* wq   = (const float*)d_in[5];
  const float* bq   = (const float*)d_in[6];
  const float* wk   = (const float*)d_in[7];
  const float* bk   = (const float*)d_in[8];
  const float* wv   = (const float*)d_in[9];
  const float* bv   = (const float*)d_in[10];
  const float* pw1  = (const float*)d_in[11];
  const float* pb1  = (const float*)d_in[12];
  const float* pw2  = (const float*)d_in[13];
  const float* pb2  = (const float*)d_in[14];
  const float* aw   = (const float*)d_in[15];
  const float* ab   = (const float*)d_in[16];
  const float* ow   = (const float*)d_in[17];
  const float* ob   = (const float*)d_in[18];
  const float* l1g  = (const float*)d_in[19];
  const float* l1b  = (const float*)d_in[20];
  const float* l2g  = (const float*)d_in[21];
  const float* l2b  = (const float*)d_in[22];
  const float* fw1  = (const float*)d_in[23];
  const float* fb1  = (const float*)d_in[24];
  const float* fw2  = (const float*)d_in[25];
  const float* fb2  = (const float*)d_in[26];
  const float* cw   = (const float*)d_in[27];
  const float* cb   = (const float*)d_in[28];
  const float* cg   = (const float*)d_in[29];
  const float* cbeta= (const float*)d_in[30];
  const float* f1w  = (const float*)d_in[31];
  const float* f1b  = (const float*)d_in[32];
  const float* b1g  = (const float*)d_in[33];
  const float* b1b  = (const float*)d_in[34];
  const float* f2w  = (const float*)d_in[35];
  const float* f2b  = (const float*)d_in[36];
  const float* b2g  = (const float*)d_in[37];
  const float* b2b  = (const float*)d_in[38];
  const float* f3w  = (const float*)d_in[39];
  const float* f3b  = (const float*)d_in[40];

  const size_t P = (size_t)BB * NN;       // 32768 points
  float* ws = (float*)d_ws;
  float* h = ws;                          // P*64
  float* q = h + P * 64;
  float* k = q + P * 64;
  float* v = k + P * 64;
  int* idx = (int*)(v + P * 64);          // P*8 ints
  float* g = (float*)(idx + P * 8);       // B*128
  float* t = q;                           // alias: safe (same-point read-then-write)

  zero_kernel<<<1, BB * 128, 0, stream>>>(g);
  embed_kernel<<<(int)(P / 4), 256, 0, stream>>>(x, ew1, eb1, ew2, eb2, h);
  knn_kernel<<<BB * (NN / QPB), 256, 0, stream>>>(x, idx);
  for (int l = 0; l < 2; l++) {
    qkv_kernel<<<QKV_GRID, 256, 0, stream>>>(h, wq + l * DD * DD, bq + l * DD,
                                             wk + l * DD * DD, bk + l * DD,
                                             wv + l * DD * DD, bv + l * DD, q, k, v);
    attn_kernel<<<ATTN_GRID, 256, 0, stream>>>(x, h, q, k, v, idx,
                                               pw1 + l * 3 * DD, pb1 + l * DD,
                                               pw2 + l * DD * DD, pb2 + l * DD,
                                               aw + l * DD, ab + l,
                                               ow + l * DD * DD, ob + l * DD,
                                               l1g + l * DD, l1b + l * DD, t);
    ffn_kernel<<<FFN_GRID, 256, 0, stream>>>(t, fw1 + l * DD * 2 * DD, fb1 + l * 2 * DD,
                                             fw2 + l * 2 * DD * DD, fb2 + l * DD,
                                             l2g + l * DD, l2b + l * DD, h);
  }
  cls_kernel<<<BB * 128, 256, 0, stream>>>(h, cw, cb, cg, cbeta, g);
  head_kernel<<<BB, 128, 0, stream>>>(g, f1w, f1b, b1g, b1b, f2w, f2b, b2g, b2b, f3w, f3b,
                                      (float*)d_out);
}

// Round 4
// 523.724 us; speedup vs baseline: 1.6358x; 1.0247x over previous
//
#include <hip/hip_runtime.h>
#include <cmath>

#define BB 8
#define NN 4096
#define DD 64
#define KK 8
#define NCLS 2

constexpr float LNEPS = 1e-5f;
constexpr float BNRS = 0.9999950000374994f;      // 1/sqrt(1+1e-5)
constexpr float INVSQRT2 = 0.70710678118654752440f;

constexpr int QKV_GRID = 512;
constexpr int ATTN_GRID = 1024;
constexpr int FFN_GRID = 512;

// knn decomposition: 64 queries/block x 8 candidate-splits (one per wave)
#define QPB 64
#define SPLITS 8

__device__ __forceinline__ float wave_sum(float v) {
#pragma unroll
  for (int m = 32; m > 0; m >>= 1) v += __shfl_xor(v, m, 64);
  return v;
}

__device__ __forceinline__ float gelu_exact(float x) {
  return 0.5f * x * (1.0f + erff(x * INVSQRT2));
}

// ---------------------------------------------------------------- zero g
__global__ void zero_kernel(float* g) { g[threadIdx.x] = 0.0f; }

// ---------------------------------------------------------------- embed: h = relu(x@ew1+eb1)@ew2+eb2
__global__ __launch_bounds__(256) void embed_kernel(
    const float* __restrict__ x, const float* __restrict__ ew1, const float* __restrict__ eb1,
    const float* __restrict__ ew2, const float* __restrict__ eb2, float* __restrict__ h) {
  __shared__ float h1[4][DD];
  int w = threadIdx.x >> 6, c = threadIdx.x & 63;
  int pt = blockIdx.x * 4 + w;
  const float* xp = x + (size_t)pt * 3;
  float x0 = xp[0], x1 = xp[1], x2 = xp[2];
  float a = fmaf(x0, ew1[c], fmaf(x1, ew1[64 + c], fmaf(x2, ew1[128 + c], eb1[c])));
  h1[w][c] = fmaxf(a, 0.0f);
  __syncthreads();
  float s = eb2[c];
#pragma unroll 8
  for (int d = 0; d < DD; d++) s = fmaf(h1[w][d], ew2[d * 64 + c], s);
  h[(size_t)pt * 64 + c] = s;
}

// ---------------------------------------------------------------- knn prep: ppg[b*N+j] = (x,y,z,|p|^2)
__global__ __launch_bounds__(256) void knn_prep_kernel(const float* __restrict__ x,
                                                       float4* __restrict__ ppg) {
  int i = blockIdx.x * 256 + threadIdx.x;
  float a0 = x[3 * i + 0], a1 = x[3 * i + 1], a2 = x[3 * i + 2];
  ppg[i] = make_float4(a0, a1, a2, a0 * a0 + a1 * a1 + a2 * a2);
}

// ---------------------------------------------------------------- knn: top-8 smallest d2 (stable ties)
// 512 blocks x 512 thr: 64 queries/block, candidates split 8-way across waves.
// Key = double(hi=float bits of d2, lo=index): strict total order, index tie-break.
// Insertion via min/max network (15 f64 ops); cross-split shared threshold prunes
// the per-wave trigger rate; stable merge of 64 partial entries per query.
__global__ __launch_bounds__(512) void knn_kernel(const float4* __restrict__ ppg,
                                                  int* __restrict__ idx) {
  __shared__ double mb[SPLITS * 8][QPB];   // 32 KB partial lists
  __shared__ double thb[SPLITS][QPB];      // 4 KB threshold exchange
  int b = blockIdx.x >> 6;                 // 64 blocks per batch
  int qbase = (blockIdx.x & 63) * QPB;
  const float4* pb = ppg + (size_t)b * NN;
  int ql = threadIdx.x & 63;
  int sp = threadIdx.x >> 6;               // split id == wave id
  float4 qp = pb[qbase + ql];
  double bd[8];
#pragma unroll
  for (int u = 0; u < 8; u++) bd[u] = INFINITY;
  double sthr = INFINITY;
  double eff = INFINITY;
  int j = sp * (NN / SPLITS);
  for (int chunk = 0; chunk < (NN / SPLITS) / 64; ++chunk) {
#pragma unroll 4
    for (int jj = 0; jj < 64; ++jj, ++j) {
      float4 pj = pb[j];
      float dot = qp.x * pj.x + qp.y * pj.y + qp.z * pj.z;
      float d2 = qp.w - 2.0f * dot + pj.w;
      double key = __hiloint2double(__float_as_int(d2), j);
      if (key < eff) {
#pragma unroll
        for (int u = 7; u > 0; --u) bd[u] = fmin(bd[u], fmax(bd[u - 1], key));
        bd[0] = fmin(bd[0], key);
        eff = fmin(bd[7], sthr);
      }
    }
    // refresh shared pruning threshold: min over splits of per-split 8th-best
    thb[sp][ql] = bd[7];
    __syncthreads();
    double s = thb[0][ql];
#pragma unroll
    for (int u = 1; u < SPLITS; u++) s = fmin(s, thb[u][ql]);
    sthr = s;
    eff = fmin(bd[7], sthr);
    __syncthreads();
  }
#pragma unroll
  for (int u = 0; u < 8; u++) mb[sp * 8 + u][ql] = bd[u];
  __syncthreads();
  if (threadIdx.x < QPB) {
    int qq = threadIdx.x;
    double cd[8];
#pragma unroll
    for (int u = 0; u < 8; u++) cd[u] = INFINITY;
    for (int e = 0; e < SPLITS * 8; e++) {
      double key = mb[e][qq];
      if (key < cd[7]) {
#pragma unroll
        for (int u = 7; u > 0; --u) cd[u] = fmin(cd[u], fmax(cd[u - 1], key));
        cd[0] = fmin(cd[0], key);
      }
    }
    int* op = idx + ((size_t)b * NN + qbase + qq) * 8;
#pragma unroll
    for (int u = 0; u < 8; u++) op[u] = __double2loint(cd[u]);
  }
}

// ---------------------------------------------------------------- qkv projection (4 points per wave)
__global__ __launch_bounds__(256) void qkv_kernel(
    const float* __restrict__ h, const float* __restrict__ wq, const float* __restrict__ bq,
    const float* __restrict__ wk, const float* __restrict__ bk,
    const float* __restrict__ wv, const float* __restrict__ bv,
    float* __restrict__ q, float* __restrict__ k, float* __restrict__ v) {
  __shared__ float lwq[DD * DD], lwk[DD * DD], lwv[DD * DD];
  __shared__ float lbq[DD], lbk[DD], lbv[DD];
  __shared__ __attribute__((aligned(16))) float hb[4][DD][4];
  int tid = threadIdx.x;
  for (int i = tid; i < DD * DD; i += 256) { lwq[i] = wq[i]; lwk[i] = wk[i]; lwv[i] = wv[i]; }
  if (tid < DD) { lbq[tid] = bq[tid]; lbk[tid] = bk[tid]; lbv[tid] = bv[tid]; }
  __syncthreads();
  int w = tid >> 6, c = tid & 63;
  constexpr int ITERS = (BB * NN) / (QKV_GRID * 16);
  for (int it = 0; it < ITERS; ++it) {
    int wid = it * (QKV_GRID * 4) + blockIdx.x * 4 + w;
    int p0 = wid * 4;
    __syncthreads();
#pragma unroll
    for (int i = 0; i < 4; i++) hb[w][c][i] = h[(size_t)(p0 + i) * 64 + c];
    __syncthreads();
    float aq[4], ak[4], av[4];
#pragma unroll
    for (int i = 0; i < 4; i++) { aq[i] = lbq[c]; ak[i] = lbk[c]; av[i] = lbv[c]; }
#pragma unroll 4
    for (int d = 0; d < DD; d++) {
      float wq_ = lwq[d * 64 + c], wk_ = lwk[d * 64 + c], wv_ = lwv[d * 64 + c];
      float4 hh = *(const float4*)&hb[w][d][0];
      aq[0] = fmaf(hh.x, wq_, aq[0]); aq[1] = fmaf(hh.y, wq_, aq[1]);
      aq[2] = fmaf(hh.z, wq_, aq[2]); aq[3] = fmaf(hh.w, wq_, aq[3]);
      ak[0] = fmaf(hh.x, wk_, ak[0]); ak[1] = fmaf(hh.y, wk_, ak[1]);
      ak[2] = fmaf(hh.z, wk_, ak[2]); ak[3] = fmaf(hh.w, wk_, ak[3]);
      av[0] = fmaf(hh.x, wv_, av[0]); av[1] = fmaf(hh.y, wv_, av[1]);
      av[2] = fmaf(hh.z, wv_, av[2]); av[3] = fmaf(hh.w, wv_, av[3]);
    }
#pragma unroll
    for (int i = 0; i < 4; i++) {
      q[(size_t)(p0 + i) * 64 + c] = aq[i];
      k[(size_t)(p0 + i) * 64 + c] = ak[i];
      v[(size_t)(p0 + i) * 64 + c] = av[i];
    }
  }
}

// ---------------------------------------------------------------- attention (1 point per wave) -> t = ln1(attn+x)
// NOTE: t may alias q (same-point read-then-write only) -> no __restrict__ on q/t.
__global__ __launch_bounds__(256) void attn_kernel(
    const float* __restrict__ x, const float* __restrict__ h,
    const float* q, const float* __restrict__ kk, const float* __restrict__ vv,
    const int* __restrict__ idx,
    const float* __restrict__ pw1, const float* __restrict__ pb1,
    const float* __restrict__ pw2, const float* __restrict__ pb2,
    const float* __restrict__ aw, const float* __restrict__ ab,
    const float* __restrict__ ow, const float* __restrict__ ob,
    const float* __restrict__ l1g, const float* __restrict__ l1b,
    float* t) {
  __shared__ float lpw2[DD * DD], low[DD * DD];
  __shared__ float lpw1[3 * DD], lpb1[DD], lpb2[DD], law[DD], lob[DD], ll1g[DD], ll1b[DD];
  __shared__ __attribute__((aligned(16))) float h1lo[4][DD][4], h1hi[4][DD][4];
  __shared__ __attribute__((aligned(16))) float outb[4][DD];
  int tid = threadIdx.x;
  for (int i = tid; i < DD * DD; i += 256) { lpw2[i] = pw2[i]; low[i] = ow[i]; }
  if (tid < 3 * DD) lpw1[tid] = pw1[tid];
  if (tid < DD) {
    lpb1[tid] = pb1[tid]; lpb2[tid] = pb2[tid]; law[tid] = aw[tid];
    lob[tid] = ob[tid]; ll1g[tid] = l1g[tid]; ll1b[tid] = l1b[tid];
  }
  float lab = ab[0];
  __syncthreads();
  int w = tid >> 6, c = tid & 63;
  constexpr int ITERS = (BB * NN) / (ATTN_GRID * 4);
  for (int it = 0; it < ITERS; ++it) {
    int p = (it * ATTN_GRID + blockIdx.x) * 4 + w;
    int b = p >> 12;
    int n = p & (NN - 1);
    const float* xb = x + (size_t)b * NN * 3;
    float hs = h[(size_t)p * 64 + c];
    float qs = q[(size_t)p * 64 + c];
    float px0 = xb[n * 3 + 0], px1 = xb[n * 3 + 1], px2 = xb[n * 3 + 2];
    int nb[8];
#pragma unroll
    for (int u = 0; u < 8; u++) nb[u] = idx[(size_t)p * 8 + u];
    __syncthreads();
#pragma unroll
    for (int u = 0; u < 8; u++) {
      int m = nb[u];
      float d0 = px0 - xb[m * 3 + 0], d1 = px1 - xb[m * 3 + 1], d2 = px2 - xb[m * 3 + 2];
      float h1 = fmaf(d0, lpw1[c], fmaf(d1, lpw1[64 + c], fmaf(d2, lpw1[128 + c], lpb1[c])));
      h1 = fmaxf(h1, 0.0f);
      if (u < 4) h1lo[w][c][u] = h1; else h1hi[w][c][u - 4] = h1;
    }
    __syncthreads();
    float acc[8];
#pragma unroll
    for (int u = 0; u < 8; u++) acc[u] = lpb2[c];
#pragma unroll 4
    for (int d = 0; d < DD; d++) {
      float wv_ = lpw2[d * 64 + c];
      float4 lo = *(const float4*)&h1lo[w][d][0];
      float4 hi = *(const float4*)&h1hi[w][d][0];
      acc[0] = fmaf(lo.x, wv_, acc[0]); acc[1] = fmaf(lo.y, wv_, acc[1]);
      acc[2] = fmaf(lo.z, wv_, acc[2]); acc[3] = fmaf(lo.w, wv_, acc[3]);
      acc[4] = fmaf(hi.x, wv_, acc[4]); acc[5] = fmaf(hi.y, wv_, acc[5]);
      acc[6] = fmaf(hi.z, wv_, acc[6]); acc[7] = fmaf(hi.w, wv_, acc[7]);
    }
    float lg[8];
#pragma unroll
    for (int u = 0; u < 8; u++) {
      float kv = kk[((size_t)(b << 12) + nb[u]) * 64 + c];
      float ai = qs - kv + acc[u];
      lg[u] = wave_sum(ai * law[c]) + lab;
    }
    float mx = lg[0];
#pragma unroll
    for (int u = 1; u < 8; u++) mx = fmaxf(mx, lg[u]);
    float ssum = 0.0f;
#pragma unroll
    for (int u = 0; u < 8; u++) { lg[u] = expf(lg[u] - mx); ssum += lg[u]; }
    float inv = 1.0f / ssum;
    float out = 0.0f;
#pragma unroll
    for (int u = 0; u < 8; u++) {
      float vg = vv[((size_t)(b << 12) + nb[u]) * 64 + c];
      out = fmaf(lg[u] * inv, vg + acc[u], out);
    }
    outb[w][c] = out;
    __syncthreads();
    float at = lob[c];
#pragma unroll 4
    for (int d = 0; d < DD; d += 4) {
      float4 ov = *(const float4*)&outb[w][d];
      at = fmaf(ov.x, low[(d + 0) * 64 + c], at);
      at = fmaf(ov.y, low[(d + 1) * 64 + c], at);
      at = fmaf(ov.z, low[(d + 2) * 64 + c], at);
      at = fmaf(ov.w, low[(d + 3) * 64 + c], at);
    }
    float res = at + hs;
    float mean = wave_sum(res) * (1.0f / 64.0f);
    float dv = res - mean;
    float var = wave_sum(dv * dv) * (1.0f / 64.0f);
    float ivr = 1.0f / sqrtf(var + LNEPS);
    t[(size_t)p * 64 + c] = fmaf(ll1g[c], dv * ivr, ll1b[c]);
  }
}

// ---------------------------------------------------------------- ffn (4 points per wave) -> h = ln2(t + ffn(t))
__global__ __launch_bounds__(256) void ffn_kernel(
    const float* __restrict__ t, const float* __restrict__ fw1, const float* __restrict__ fb1,
    const float* __restrict__ fw2, const float* __restrict__ fb2,
    const float* __restrict__ l2g, const float* __restrict__ l2b, float* __restrict__ h) {
  __shared__ float lf1[DD * 128];
  __shared__ float lf2[128 * DD];
  __shared__ float lb1[128], lb2[DD], lg2[DD], lbt2[DD];
  __shared__ __attribute__((aligned(16))) float yb[4][DD][4];
  __shared__ __attribute__((aligned(16))) float hb[4][128][4];
  int tid = threadIdx.x;
  for (int i = tid; i < DD * 128; i += 256) { lf1[i] = fw1[i]; lf2[i] = fw2[i]; }
  if (tid < 128) lb1[tid] = fb1[tid];
  if (tid < DD) { lb2[tid] = fb2[tid]; lg2[tid] = l2g[tid]; lbt2[tid] = l2b[tid]; }
  __syncthreads();
  int w = tid >> 6, c = tid & 63;
  constexpr int ITERS = (BB * NN) / (FFN_GRID * 16);
  for (int it = 0; it < ITERS; ++it) {
    int wid = it * (FFN_GRID * 4) + blockIdx.x * 4 + w;
    int p0 = wid * 4;
    float y[4];
    __syncthreads();
#pragma unroll
    for (int i = 0; i < 4; i++) { y[i] = t[(size_t)(p0 + i) * 64 + c]; yb[w][c][i] = y[i]; }
    __syncthreads();
    float hA[4], hB[4];
#pragma unroll
    for (int i = 0; i < 4; i++) { hA[i] = lb1[c]; hB[i] = lb1[64 + c]; }
#pragma unroll 4
    for (int d = 0; d < DD; d++) {
      float w0 = lf1[d * 128 + c], w1 = lf1[d * 128 + 64 + c];
      float4 yv = *(const float4*)&yb[w][d][0];
      hA[0] = fmaf(yv.x, w0, hA[0]); hA[1] = fmaf(yv.y, w0, hA[1]);
      hA[2] = fmaf(yv.z, w0, hA[2]); hA[3] = fmaf(yv.w, w0, hA[3]);
      hB[0] = fmaf(yv.x, w1, hB[0]); hB[1] = fmaf(yv.y, w1, hB[1]);
      hB[2] = fmaf(yv.z, w1, hB[2]); hB[3] = fmaf(yv.w, w1, hB[3]);
    }
#pragma unroll
    for (int i = 0; i < 4; i++) {
      hA[i] = gelu_exact(hA[i]); hB[i] = gelu_exact(hB[i]);
      hb[w][c][i] = hA[i]; hb[w][64 + c][i] = hB[i];
    }
    __syncthreads();
    float o[4];
#pragma unroll
    for (int i = 0; i < 4; i++) o[i] = lb2[c];
#pragma unroll 4
    for (int j = 0; j < 128; j++) {
      float wv_ = lf2[j * 64 + c];
      float4 hv = *(const float4*)&hb[w][j][0];
      o[0] = fmaf(hv.x, wv_, o[0]); o[1] = fmaf(hv.y, wv_, o[1]);
      o[2] = fmaf(hv.z, wv_, o[2]); o[3] = fmaf(hv.w, wv_, o[3]);
    }
#pragma unroll
    for (int i = 0; i < 4; i++) {
      float r = y[i] + o[i];
      float mean = wave_sum(r) * (1.0f / 64.0f);
      float dv = r - mean;
      float var = wave_sum(dv * dv) * (1.0f / 64.0f);
      float ivr = 1.0f / sqrtf(var + LNEPS);
      h[(size_t)(p0 + i) * 64 + c] = fmaf(lg2[c], dv * ivr, lbt2[c]);
    }
  }
}

// ---------------------------------------------------------------- classifier proj + blockwise max-pool
__global__ __launch_bounds__(256) void cls_kernel(
    const float* __restrict__ h, const float* __restrict__ cw, const float* __restrict__ cb,
    const float* __restrict__ cg, const float* __restrict__ cbeta, float* __restrict__ g) {
  __shared__ float lcw[DD * 128];
  __shared__ float lcb[128], lcg[128], lcbt[128];
  __shared__ __attribute__((aligned(16))) float hb[4][DD][4];
  __shared__ float wmax[4][128];
  int tid = threadIdx.x;
  for (int i = tid; i < DD * 128; i += 256) lcw[i] = cw[i];
  if (tid < 128) { lcb[tid] = cb[tid]; lcg[tid] = cg[tid]; lcbt[tid] = cbeta[tid]; }
  __syncthreads();
  int w = tid >> 6, c = tid & 63;
  int b = blockIdx.x >> 7;            // 128 blocks per batch
  int blk = blockIdx.x & 127;
  int base = b * NN + blk * 32;
  float m0 = 0.0f, m1 = 0.0f;
  for (int it = 0; it < 2; ++it) {
    int p0 = base + (w * 2 + it) * 4;
    __syncthreads();
#pragma unroll
    for (int i = 0; i < 4; i++) hb[w][c][i] = h[(size_t)(p0 + i) * 64 + c];
    __syncthreads();
    float a0[4], a1[4];
#pragma unroll
    for (int i = 0; i < 4; i++) { a0[i] = lcb[c]; a1[i] = lcb[64 + c]; }
#pragma unroll 4
    for (int d = 0; d < DD; d++) {
      float w0 = lcw[d * 128 + c], w1 = lcw[d * 128 + 64 + c];
      float4 hv = *(const float4*)&hb[w][d][0];
      a0[0] = fmaf(hv.x, w0, a0[0]); a0[1] = fmaf(hv.y, w0, a0[1]);
      a0[2] = fmaf(hv.z, w0, a0[2]); a0[3] = fmaf(hv.w, w0, a0[3]);
      a1[0] = fmaf(hv.x, w1, a1[0]); a1[1] = fmaf(hv.y, w1, a1[1]);
      a1[2] = fmaf(hv.z, w1, a1[2]); a1[3] = fmaf(hv.w, w1, a1[3]);
    }
#pragma unroll
    for (int i = 0; i < 4; i++) {
      m0 = fmaxf(m0, fmaxf(0.0f, fmaf(lcg[c] * a0[i], BNRS, lcbt[c])));
      m1 = fmaxf(m1, fmaxf(0.0f, fmaf(lcg[64 + c] * a1[i], BNRS, lcbt[64 + c])));
    }
  }
  wmax[w][c] = m0; wmax[w][64 + c] = m1;
  __syncthreads();
  if (tid < 128) {
    float mm = fmaxf(fmaxf(wmax[0][tid], wmax[1][tid]), fmaxf(wmax[2][tid], wmax[3][tid]));
    atomicMax((int*)&g[b * 128 + tid], __float_as_int(mm));  // values >= 0
  }
}

// ---------------------------------------------------------------- final head (per batch)
__global__ __launch_bounds__(128) void head_kernel(
    const float* __restrict__ g,
    const float* __restrict__ f1w, const float* __restrict__ f1b,
    const float* __restrict__ b1g, const float* __restrict__ b1b,
    const float* __restrict__ f2w, const float* __restrict__ f2b,
    const float* __restrict__ b2g, const float* __restrict__ b2b,
    const float* __restrict__ f3w, const float* __restrict__ f3b,
    float* __restrict__ out) {
  __shared__ float gb[128], g1[128], g2[64];
  int b = blockIdx.x, t = threadIdx.x;
  gb[t] = g[b * 128 + t];
  __syncthreads();
  float a = f1b[t];
#pragma unroll 4
  for (int d = 0; d < 128; d++) a = fmaf(gb[d], f1w[d * 128 + t], a);
  g1[t] = fmaxf(0.0f, fmaf(b1g[t] * a, BNRS, b1b[t]));
  __syncthreads();
  if (t < 64) {
    float a2 = f2b[t];
#pragma unroll 4
    for (int j = 0; j < 128; j++) a2 = fmaf(g1[j], f2w[j * 64 + t], a2);
    g2[t] = fmaxf(0.0f, fmaf(b2g[t] * a2, BNRS, b2b[t]));
  }
  __syncthreads();
  if (t < NCLS) {
    float a3 = f3b[t];
#pragma unroll
    for (int d = 0; d < 64; d++) a3 = fmaf(g2[d], f3w[d * NCLS + t], a3);
    out[b * NCLS + t] = a3;
  }
}

extern "C" void kernel_launch(void* const* d_in, const int* in_sizes, int n_in,
                              void* d_out, int out_size, void* d_ws, size_t ws_size,
                              hipStream_t stream) {
  const float* x    = (const float*)d_in[0];
  const float* ew1  = (const float*)d_in[1];
  const float* eb1  = (const float*)d_in[2];
  const float* ew2  = (const float*)d_in[3];
  const float* eb2  = (const float*)d_in[4];
  const float* wq   = (const float*)d_in[5];
  const float* bq   = (const float*)d_in[6];
  const float* wk   = (const float*)d_in[7];
  const float* bk   = (const float*)d_in[8];
  const float* wv   = (const float*)d_in[9];
  const float* bv   = (const float*)d_in[10];
  const float* pw1  = (const float*)d_in[11];
  const float* pb1  = (const float*)d_in[12];
  const float* pw2  = (const float*)d_in[13];
  const float* pb2  = (const float*)d_in[14];
  const float* aw   = (const float*)d_in[15];
  const float* ab   = (const float*)d_in[16];
  const float* ow   = (const float*)d_in[17];
  const float* ob   = (const float*)d_in[18];
  const float* l1g  = (const float*)d_in[19];
  const float* l1b  = (const float*)d_in[20];
  const float* l2g  = (const float*)d_in[21];
  const float* l2b  = (const float*)d_in[22];
  const float* fw1  = (const float*)d_in[23];
  const float* fb1  = (const float*)d_in[24];
  const float* fw2  = (const float*)d_in[25];
  const float* fb2  = (const float*)d_in[26];
  const float* cw   = (const float*)d_in[27];
  const float* cb   = (const float*)d_in[28];
  const float* cg   = (const float*)d_in[29];
  const float* cbeta= (const float*)d_in[30];
  const float* f1w  = (const float*)d_in[31];
  const float* f1b  = (const float*)d_in[32];
  const float* b1g  = (const float*)d_in[33];
  const float* b1b  = (const float*)d_in[34];
  const float* f2w  = (const float*)d_in[35];
  const float* f2b  = (const float*)d_in[36];
  const float* b2g  = (const float*)d_in[37];
  const float* b2b  = (const float*)d_in[38];
  const float* f3w  = (const float*)d_in[39];
  const float* f3b  = (const float*)d_in[40];

  const size_t P = (size_t)BB * NN;       // 32768 points
  float* ws = (float*)d_ws;
  float* h = ws;                          // P*64
  float* q = h + P * 64;
  float* k = q + P * 64;
  float* v = k + P * 64;
  int* idx = (int*)(v + P * 64);          // P*8 ints
  float* g = (float*)(idx + P * 8);       // B*128
  float4* ppg = (float4*)(g + BB * 128);  // P float4 (aligned: offset is 16B-multiple)
  float* t = q;                           // alias: safe (same-point read-then-write)

  zero_kernel<<<1, BB * 128, 0, stream>>>(g);
  embed_kernel<<<(int)(P / 4), 256, 0, stream>>>(x, ew1, eb1, ew2, eb2, h);
  knn_prep_kernel<<<(int)(P / 256), 256, 0, stream>>>(x, ppg);
  knn_kernel<<<BB * (NN / QPB), 512, 0, stream>>>(ppg, idx);
  for (int l = 0; l < 2; l++) {
    qkv_kernel<<<QKV_GRID, 256, 0, stream>>>(h, wq + l * DD * DD, bq + l * DD,
                                             wk + l * DD * DD, bk + l * DD,
                                             wv + l * DD * DD, bv + l * DD, q, k, v);
    attn_kernel<<<ATTN_GRID, 256, 0, stream>>>(x, h, q, k, v, idx,
                                               pw1 + l * 3 * DD, pb1 + l * DD,
                                               pw2 + l * DD * DD, pb2 + l * DD,
                                               aw + l * DD, ab + l,
                                               ow + l * DD * DD, ob + l * DD,
                                               l1g + l * DD, l1b + l * DD, t);
    ffn_kernel<<<FFN_GRID, 256, 0, stream>>>(t, fw1 + l * DD * 2 * DD, fb1 + l * 2 * DD,
                                             fw2 + l * 2 * DD * DD, fb2 + l * DD,
                                             l2g + l * DD, l2b + l * DD, h);
  }
  cls_kernel<<<BB * 128, 256, 0, stream>>>(h, cw, cb, cg, cbeta, g);
  head_kernel<<<BB, 128, 0, stream>>>(g, f1w, f1b, b1g, b1b, f2w, f2b, b2g, b2b, f3w, f3b,
                                      (float*)d_out);
}